// Round 16
// baseline (222.586 us; speedup 1.0000x reference)
//
#include <hip/hip_runtime.h>
#include <hip/hip_bf16.h>

// Problem constants (B=1)
#define T_ 8
#define H_ 64
#define W_ 64
#define C_ 64
#define HW_ (H_ * W_)          // 4096
#define THW_ (T_ * H_ * W_)    // 32768
#define KTAPS 27
#define KDIM (C_ * KTAPS)      // 1728
#define NOFF 54
#define CHS 70                 // padded LDS channel stride (bf16) for deform staging
#define OSTR 56                // LDS offsets panel stride (floats)

typedef __bf16 bf16x8 __attribute__((ext_vector_type(8)));
typedef float floatx4 __attribute__((ext_vector_type(4)));

// ---------------------------------------------------------------------------
// prep + to_cl merged: one launch, disjoint outputs.
//  ws[tap*4096 + g16*1024 + s*512 + lane*8 + j]
//    = W[co = g16*16 + (lane&15)][cin = s*32 + (lane>>4)*8 + j][tap]
// ---------------------------------------------------------------------------
__global__ __launch_bounds__(256) void prep_tocl_kernel(
    const float* __restrict__ x, __hip_bfloat16* __restrict__ xcl,
    const float* __restrict__ w1, const float* __restrict__ woff,
    const float* __restrict__ wd, const float* __restrict__ wr,
    __hip_bfloat16* __restrict__ w1s, __hip_bfloat16* __restrict__ woffs,
    __hip_bfloat16* __restrict__ wds, __hip_bfloat16* __restrict__ wrs) {
    __shared__ float tile[64][65];
    const int tid = threadIdx.x;

    {
        int i = blockIdx.x * 256 + tid;
        if (i < C_ * KDIM) {
            int j = i & 7, lane = (i >> 3) & 63, s = (i >> 9) & 1, g16 = (i >> 10) & 3, tap = i >> 12;
            int co = g16 * 16 + (lane & 15);
            int cin = s * 32 + (lane >> 4) * 8 + j;
            int src = (co * C_ + cin) * KTAPS + tap;
            w1s[i] = __float2bfloat16(w1[src]);
            woffs[i] = (co < NOFF) ? __float2bfloat16(woff[src]) : __float2bfloat16(0.f);
            wds[i] = __float2bfloat16(wd[src]);
        }
        if (i < C_ * C_) {
            int j = i & 7, lane = (i >> 3) & 63, s = (i >> 9) & 1, g16 = i >> 10;
            int co = g16 * 16 + (lane & 15);
            int cin = s * 32 + (lane >> 4) * 8 + j;
            wrs[i] = __float2bfloat16(wr[co * C_ + cin]);
        }
    }

    const int pos0 = blockIdx.x * 64;
    for (int i = tid; i < 4096; i += 256) {
        int ch = i >> 6, p = i & 63;
        tile[ch][p] = x[ch * THW_ + pos0 + p];
    }
    __syncthreads();
    for (int i = tid; i < 4096; i += 256) {
        int p = i >> 6, ch = i & 63;
        xcl[(pos0 + p) * C_ + ch] = __float2bfloat16(tile[ch][p]);
    }
}

// ---------------------------------------------------------------------------
// BARRIER-FREE per-wave streaming MFMA 3x3x3 conv (conv1) — R16: 2x waves.
//  Block = (t,h,w-QUARTER): 16 pos x 64 co, 4 waves each 16 pos x 16 co
//  (chf = wv). Grid T*H*4 = 2048 -> 8192 waves = 8/SIMD (was 4/SIMD).
//  A-loads duplicated 4x across waves (affine, L1-absorbed — R11 lesson);
//  per-16-pos B-instruction count unchanged. Branchy kh kept (R13 lesson).
// ---------------------------------------------------------------------------
__global__ __launch_bounds__(256) void conv_stream_kernel(
    const __hip_bfloat16* __restrict__ in_cl,
    const __hip_bfloat16* __restrict__ wTs,   // swizzled (27*4096)
    const float* __restrict__ bias,
    __hip_bfloat16* __restrict__ out_cl_b16) {
    __shared__ __hip_bfloat16 ts[16 * 72];    // 2304B bounce

    const int tid = threadIdx.x;
    const int chf = tid >> 6;                 // this wave's 16-co group
    const int lane = tid & 63;
    const int l15 = lane & 15;
    const int quad = lane >> 4;
    const int wq = blockIdx.x & 3;
    const int h = (blockIdx.x >> 2) & 63;
    const int t = blockIdx.x >> 8;
    const int w0 = wq * 16;
    const int wpos = w0 + l15;                // this lane's w position (A row)
    const int posbase = t * HW_ + h * W_;

    floatx4 acc = (floatx4){0.f, 0.f, 0.f, 0.f};
    const bf16x8 z = {};
    const __hip_bfloat16* wb = wTs + chf * 1024 + lane * 8;

    const int ktlo = (t == 0) ? 1 : 0;
    const int kthi = (t == T_ - 1) ? 2 : 3;

    for (int kt = ktlo; kt < kthi; ++kt) {
        const int t_in = t - 1 + kt;
#pragma unroll 1
        for (int kh = 0; kh < 3; ++kh) {
            const int h_in = h - 1 + kh;
            if ((unsigned)h_in >= H_) continue;           // block-uniform
            const int rowbase = t_in * HW_ + h_in * W_;
#pragma unroll
            for (int kw = 0; kw < 3; ++kw) {
                const int tap = kt * 9 + kh * 3 + kw;
                const int w_in = wpos - 1 + kw;
                const bool v = (unsigned)w_in < W_;       // per-lane edge
                const int wc = v ? w_in : 0;
                const __hip_bfloat16* ap = in_cl + (rowbase + wc) * C_ + quad * 8;
                bf16x8 a0 = *(const bf16x8*)(ap);
                bf16x8 a1 = *(const bf16x8*)(ap + 32);
                a0 = v ? a0 : z;
                a1 = v ? a1 : z;
                const __hip_bfloat16* bp = wb + tap * 4096;
                const bf16x8 b0 = *(const bf16x8*)(bp);          // s=0
                const bf16x8 b1 = *(const bf16x8*)(bp + 512);    // s=1
                acc = __builtin_amdgcn_mfma_f32_16x16x32_bf16(a0, b0, acc, 0, 0, 0);
                acc = __builtin_amdgcn_mfma_f32_16x16x32_bf16(a1, b1, acc, 0, 0, 0);
            }
        }
    }

    // D layout: col(l15)=cout-within-16, row(quad*4+r)=pos-within-16
    const int n0 = chf * 16 + l15;
    const float bv = bias[n0];
#pragma unroll
    for (int r = 0; r < 4; ++r) {
        const int p = quad * 4 + r;
        float v0 = acc[r] + bv;
        v0 = (v0 >= 0.f) ? v0 : 0.01f * v0;               // lrelu
        ts[p * 72 + n0] = __float2bfloat16(v0);
    }
    __syncthreads();
    // coalesced channel-last store: 16 pos x 64 ch, 8B per thread
    {
        const int p = tid >> 4, ck = tid & 15;
        const uint2 v2 = *(const uint2*)&ts[p * 72 + ck * 4];
        *(uint2*)&out_cl_b16[(posbase + w0 + p) * C_ + ck * 4] = v2;
    }
}

// ---------------------------------------------------------------------------
// FUSED offsets-conv + deformable conv + 1x1 residual — EXACT R12 (92 µs).
//  Phase 1: per-wave streaming MFMA offsets conv -> LDS offs[32][56] (fp32).
//  Phase 2: R9 deform — cooperative LDS-staged A, named 2-deep gather
//   pipeline, swizzled B — load_off reads LDS.
// ---------------------------------------------------------------------------
struct Gath {
    bf16x8 c00, c01, c10, c11;
    float w00, w01, w10, w11;
};

__global__ __launch_bounds__(256) void deform_fused_kernel(
    const __hip_bfloat16* __restrict__ y1b,
    const __hip_bfloat16* __restrict__ woffs, const float* __restrict__ boff,
    const __hip_bfloat16* __restrict__ wds, const float* __restrict__ bd,
    const __hip_bfloat16* __restrict__ xclb, const __hip_bfloat16* __restrict__ wrs,
    const float* __restrict__ br, float* __restrict__ out) {
    __shared__ __hip_bfloat16 Abuf[2][32 * CHS];     // 8960 B
    __shared__ float offs[32 * OSTR];                // 7168 B

    const int tid = threadIdx.x;
    const int wv = tid >> 6;
    const int lane = tid & 63;
    const int l15 = lane & 15;
    const int quad = lane >> 4;
    const int wh = blockIdx.x & 1;
    const int h = (blockIdx.x >> 1) & 63;
    const int t = blockIdx.x >> 7;
    const int w0 = wh * 32;
    const int n = wv * 16 + l15;
    const int posbase = t * HW_ + h * W_ + w0;
    const int cpos = tid >> 3;               // position 0..31
    const int c8 = tid & 7;                  // 8-ch chunk

    // ================= Phase 1: offsets conv -> LDS =================
    {
        const int pg = wv >> 1;              // pos group
        const int chf = wv & 1;              // co half
        const int wpos = w0 + pg * 16 + l15;
        floatx4 oa0 = (floatx4){0.f, 0.f, 0.f, 0.f};
        floatx4 oa1 = (floatx4){0.f, 0.f, 0.f, 0.f};
        const bf16x8 z = {};
        const __hip_bfloat16* wb = woffs + chf * 2048 + lane * 8;
        const int ktlo = (t == 0) ? 1 : 0;
        const int kthi = (t == T_ - 1) ? 2 : 3;

        for (int kt = ktlo; kt < kthi; ++kt) {
            const int t_in = t - 1 + kt;
#pragma unroll 1
            for (int kh = 0; kh < 3; ++kh) {
                const int h_in = h - 1 + kh;
                if ((unsigned)h_in >= H_) continue;
                const int rowbase = t_in * HW_ + h_in * W_;
#pragma unroll
                for (int kw = 0; kw < 3; ++kw) {
                    const int tap = kt * 9 + kh * 3 + kw;
                    const int w_in = wpos - 1 + kw;
                    const bool v = (unsigned)w_in < W_;
                    const int wc = v ? w_in : 0;
                    const __hip_bfloat16* ap = y1b + (rowbase + wc) * C_ + quad * 8;
                    bf16x8 a0 = *(const bf16x8*)(ap);
                    bf16x8 a1 = *(const bf16x8*)(ap + 32);
                    a0 = v ? a0 : z;
                    a1 = v ? a1 : z;
                    const __hip_bfloat16* bp = wb + tap * 4096;
                    const bf16x8 b00 = *(const bf16x8*)(bp);
                    const bf16x8 b01 = *(const bf16x8*)(bp + 512);
                    const bf16x8 b10 = *(const bf16x8*)(bp + 1024);
                    const bf16x8 b11 = *(const bf16x8*)(bp + 1536);
                    oa0 = __builtin_amdgcn_mfma_f32_16x16x32_bf16(a0, b00, oa0, 0, 0, 0);
                    oa0 = __builtin_amdgcn_mfma_f32_16x16x32_bf16(a1, b01, oa0, 0, 0, 0);
                    oa1 = __builtin_amdgcn_mfma_f32_16x16x32_bf16(a0, b10, oa1, 0, 0, 0);
                    oa1 = __builtin_amdgcn_mfma_f32_16x16x32_bf16(a1, b11, oa1, 0, 0, 0);
                }
            }
        }
        // D layout: col(l15)=cout-within-16, row(quad*4+r)=pos-within-16
        const int n0 = chf * 32 + l15;                // 0..15 or 32..47 (<54)
        const float bv0 = boff[n0];
        const float bv1 = (n0 + 16 < NOFF) ? boff[n0 + 16] : 0.f;
#pragma unroll
        for (int r = 0; r < 4; ++r) {
            const int p = pg * 16 + quad * 4 + r;
            offs[p * OSTR + n0] = oa0[r] + bv0;
            if (n0 + 16 < NOFF) offs[p * OSTR + n0 + 16] = oa1[r] + bv1;
        }
    }
    __syncthreads();

    // ================= Phase 2: deform (R9 structure) =================
    floatx4 acc[2], racc[2];
#pragma unroll
    for (int m = 0; m < 2; ++m) {
        acc[m] = (floatx4){0.f, 0.f, 0.f, 0.f};
        racc[m] = (floatx4){0.f, 0.f, 0.f, 0.f};
    }

    // residual 1x1 conv on x (swizzled B, coalesced)
    {
        const bf16x8 rb0 = *(const bf16x8*)(wrs + wv * 1024 + lane * 8);
        const bf16x8 rb1 = *(const bf16x8*)(wrs + wv * 1024 + lane * 8 + 512);
#pragma unroll
        for (int m = 0; m < 2; ++m) {
            const __hip_bfloat16* ap = xclb + (posbase + m * 16 + l15) * C_ + quad * 8;
            const bf16x8 a0 = *(const bf16x8*)(ap);
            const bf16x8 a1 = *(const bf16x8*)(ap + 32);
            racc[m] = __builtin_amdgcn_mfma_f32_16x16x32_bf16(a0, rb0, racc[m], 0, 0, 0);
            racc[m] = __builtin_amdgcn_mfma_f32_16x16x32_bf16(a1, rb1, racc[m], 0, 0, 0);
        }
    }

    const int k0 = (t == 0) ? 9 : 0;
    const int k1 = (t == T_ - 1) ? 18 : KTAPS;

    auto load_off = [&](int k, float& dh, float& dw) {
        dh = offs[cpos * OSTR + 2 * k];
        dw = offs[cpos * OSTR + 2 * k + 1];
    };
    auto gather = [&](int k, float dh, float dw, Gath& g) {
        const int kt = k / 9, kh = (k / 3) % 3, kw = k % 3;
        const int t_in = t - 1 + kt;
        const float hs = (float)(h - 1 + kh) + dh;
        const float wsv = (float)(w0 + cpos - 1 + kw) + dw;
        const float h0f = floorf(hs), w0f = floorf(wsv);
        const float fh = hs - h0f, fw = wsv - w0f;
        const int h0i = (int)h0f, w0i = (int)w0f;
        const int h1i = h0i + 1, w1i = w0i + 1;
        const float m_h0 = ((unsigned)h0i < H_) ? 1.f : 0.f;
        const float m_h1 = ((unsigned)h1i < H_) ? 1.f : 0.f;
        const float m_w0 = ((unsigned)w0i < W_) ? 1.f : 0.f;
        const float m_w1 = ((unsigned)w1i < W_) ? 1.f : 0.f;
        g.w00 = (1.f - fh) * (1.f - fw) * m_h0 * m_w0;
        g.w01 = (1.f - fh) * fw * m_h0 * m_w1;
        g.w10 = fh * (1.f - fw) * m_h1 * m_w0;
        g.w11 = fh * fw * m_h1 * m_w1;
        const int h0c = min(max(h0i, 0), H_ - 1);
        const int h1c = min(max(h1i, 0), H_ - 1);
        const int w0c = min(max(w0i, 0), W_ - 1);
        const int w1c = min(max(w1i, 0), W_ - 1);
        const int tb = t_in * HW_;
        g.c00 = *(const bf16x8*)(y1b + (tb + h0c * W_ + w0c) * C_ + c8 * 8);
        g.c01 = *(const bf16x8*)(y1b + (tb + h0c * W_ + w1c) * C_ + c8 * 8);
        g.c10 = *(const bf16x8*)(y1b + (tb + h1c * W_ + w0c) * C_ + c8 * 8);
        g.c11 = *(const bf16x8*)(y1b + (tb + h1c * W_ + w1c) * C_ + c8 * 8);
    };
    auto blend = [&](const Gath& g, bf16x8& o) {
        union U { bf16x8 v; __hip_bfloat16 e[8]; };
        U a00, a01, a10, a11, r;
        a00.v = g.c00; a01.v = g.c01; a10.v = g.c10; a11.v = g.c11;
#pragma unroll
        for (int j = 0; j < 8; ++j) {
            float f = g.w00 * __bfloat162float(a00.e[j]) + g.w01 * __bfloat162float(a01.e[j]) +
                      g.w10 * __bfloat162float(a10.e[j]) + g.w11 * __bfloat162float(a11.e[j]);
            r.e[j] = __float2bfloat16(f);
        }
        o = r.v;
    };
    auto loadBd = [&](int k, bf16x8& B0, bf16x8& B1) {
        const __hip_bfloat16* p = wds + k * 4096 + wv * 1024 + lane * 8;
        B0 = *(const bf16x8*)(p);
        B1 = *(const bf16x8*)(p + 512);
    };

    // named pipeline state (no dynamically-indexed arrays -> no spill)
    Gath gA, gB;
    bf16x8 bl;
    bf16x8 cb0, cb1, nb0, nb1;
    float oh2, ow2;

    auto step = [&](int k, __hip_bfloat16* buf, Gath& gSelf, Gath& gOther) {
        *(bf16x8*)&buf[cpos * CHS + c8 * 8] = bl;
        if (k + 2 < k1) {
            gather(k + 2, oh2, ow2, gSelf);
            if (k + 3 < k1) load_off(k + 3, oh2, ow2);
        }
        __syncthreads();

        const bf16x8 b0 = cb0;
        const bf16x8 b1 = cb1;
#pragma unroll
        for (int m = 0; m < 2; ++m) {
            const __hip_bfloat16* ap = buf + (m * 16 + l15) * CHS + quad * 8;
            const bf16x8 a0 = *(const bf16x8*)(ap);
            const bf16x8 a1 = *(const bf16x8*)(ap + 32);
            acc[m] = __builtin_amdgcn_mfma_f32_16x16x32_bf16(a0, b0, acc[m], 0, 0, 0);
            acc[m] = __builtin_amdgcn_mfma_f32_16x16x32_bf16(a1, b1, acc[m], 0, 0, 0);
        }
        if (k + 1 < k1) {
            blend(gOther, bl);
            cb0 = nb0; cb1 = nb1;
            if (k + 2 < k1) loadBd(k + 2, nb0, nb1);
        }
    };

    // prologue: gathers 2 taps deep, B 1 tap deep
    {
        float dh0, dw0, dh1, dw1;
        load_off(k0, dh0, dw0);
        load_off(k0 + 1, dh1, dw1);
        load_off(k0 + 2, oh2, ow2);
        gather(k0, dh0, dw0, gA);
        gather(k0 + 1, dh1, dw1, gB);
        loadBd(k0, cb0, cb1);
        loadBd(k0 + 1, nb0, nb1);
        blend(gA, bl);
    }

    // main loop, 2x unrolled: even kr -> (buf0, gA), odd kr -> (buf1, gB)
    int k = k0;
    for (; k + 1 < k1; k += 2) {
        step(k, Abuf[0], gA, gB);
        step(k + 1, Abuf[1], gB, gA);
    }
    if (k < k1) step(k, Abuf[0], gA, gB);

    // epilogue: lrelu(deform + bd) + (residual + br)
    const float bdv = bd[n];
    const float brv = br[n];
#pragma unroll
    for (int m = 0; m < 2; ++m) {
        floatx4 o;
#pragma unroll
        for (int r = 0; r < 4; ++r) {
            float v = acc[m][r] + bdv;
            v = (v >= 0.f) ? v : 0.01f * v;
            o[r] = v + racc[m][r] + brv;
        }
        *(floatx4*)&out[n * THW_ + posbase + m * 16 + quad * 4] = o;
    }
}

// ---------------------------------------------------------------------------
extern "C" void kernel_launch(void* const* d_in, const int* in_sizes, int n_in,
                              void* d_out, int out_size, void* d_ws, size_t ws_size,
                              hipStream_t stream) {
    const float* x    = (const float*)d_in[0];
    const float* W1   = (const float*)d_in[1];
    const float* b1   = (const float*)d_in[2];
    const float* Woff = (const float*)d_in[3];
    const float* boff = (const float*)d_in[4];
    const float* Wd   = (const float*)d_in[5];
    const float* bd   = (const float*)d_in[6];
    const float* Wr   = (const float*)d_in[7];
    const float* br   = (const float*)d_in[8];
    float* out = (float*)d_out;

    float* ws = (float*)d_ws;
    __hip_bfloat16* xclb  = (__hip_bfloat16*)(ws);             // 2,097,152 bf16
    __hip_bfloat16* y1b   = (__hip_bfloat16*)(ws + 1048576);   // 2,097,152 bf16
    __hip_bfloat16* w1s   = (__hip_bfloat16*)(ws + 2097152);   //   110,592 bf16
    __hip_bfloat16* woffs = (__hip_bfloat16*)(ws + 2152448);   //   110,592 bf16
    __hip_bfloat16* wdsb  = (__hip_bfloat16*)(ws + 2207744);   //   110,592 bf16
    __hip_bfloat16* wrsb  = (__hip_bfloat16*)(ws + 2263040);   //     4,096 bf16
    // total ~9.1 MB

    prep_tocl_kernel<<<THW_ / 64, 256, 0, stream>>>(
        x, xclb, W1, Woff, Wd, Wr, w1s, woffs, wdsb, wrsb);

    conv_stream_kernel<<<dim3(T_ * H_ * 4), 256, 0, stream>>>(
        xclb, w1s, b1, y1b);

    deform_fused_kernel<<<dim3(T_ * H_ * 2), 256, 0, stream>>>(
        y1b, woffs, boff, wdsb, bd, xclb, wrsb, br, out);
}

// Round 17
// 200.304 us; speedup vs baseline: 1.1112x; 1.1112x over previous
//
#include <hip/hip_runtime.h>
#include <hip/hip_bf16.h>

// Problem constants (B=1)
#define T_ 8
#define H_ 64
#define W_ 64
#define C_ 64
#define HW_ (H_ * W_)          // 4096
#define THW_ (T_ * H_ * W_)    // 32768
#define KTAPS 27
#define KDIM (C_ * KTAPS)      // 1728
#define NOFF 54
#define CHS 70                 // padded LDS channel stride (bf16) for deform staging
#define OSTR 56                // LDS offsets panel stride (floats)

typedef __bf16 bf16x8 __attribute__((ext_vector_type(8)));
typedef float floatx4 __attribute__((ext_vector_type(4)));

// ---------------------------------------------------------------------------
// prep + to_cl merged: one launch, disjoint outputs.
//  ws[tap*4096 + g16*1024 + s*512 + lane*8 + j]
//    = W[co = g16*16 + (lane&15)][cin = s*32 + (lane>>4)*8 + j][tap]
// ---------------------------------------------------------------------------
__global__ __launch_bounds__(256) void prep_tocl_kernel(
    const float* __restrict__ x, __hip_bfloat16* __restrict__ xcl,
    const float* __restrict__ w1, const float* __restrict__ woff,
    const float* __restrict__ wd, const float* __restrict__ wr,
    __hip_bfloat16* __restrict__ w1s, __hip_bfloat16* __restrict__ woffs,
    __hip_bfloat16* __restrict__ wds, __hip_bfloat16* __restrict__ wrs) {
    __shared__ float tile[64][65];
    const int tid = threadIdx.x;

    {
        int i = blockIdx.x * 256 + tid;
        if (i < C_ * KDIM) {
            int j = i & 7, lane = (i >> 3) & 63, s = (i >> 9) & 1, g16 = (i >> 10) & 3, tap = i >> 12;
            int co = g16 * 16 + (lane & 15);
            int cin = s * 32 + (lane >> 4) * 8 + j;
            int src = (co * C_ + cin) * KTAPS + tap;
            w1s[i] = __float2bfloat16(w1[src]);
            woffs[i] = (co < NOFF) ? __float2bfloat16(woff[src]) : __float2bfloat16(0.f);
            wds[i] = __float2bfloat16(wd[src]);
        }
        if (i < C_ * C_) {
            int j = i & 7, lane = (i >> 3) & 63, s = (i >> 9) & 1, g16 = i >> 10;
            int co = g16 * 16 + (lane & 15);
            int cin = s * 32 + (lane >> 4) * 8 + j;
            wrs[i] = __float2bfloat16(wr[co * C_ + cin]);
        }
    }

    const int pos0 = blockIdx.x * 64;
    for (int i = tid; i < 4096; i += 256) {
        int ch = i >> 6, p = i & 63;
        tile[ch][p] = x[ch * THW_ + pos0 + p];
    }
    __syncthreads();
    for (int i = tid; i < 4096; i += 256) {
        int p = i >> 6, ch = i & 63;
        xcl[(pos0 + p) * C_ + ch] = __float2bfloat16(tile[ch][p]);
    }
}

// ---------------------------------------------------------------------------
// BARRIER-FREE per-wave streaming MFMA 3x3x3 conv (conv1) — EXACT R12 form
// (R16's w-quarter split regressed: duplicated A-loads are TA-line-bound,
// not free; 32-pos block restored).
// ---------------------------------------------------------------------------
__global__ __launch_bounds__(256) void conv_stream_kernel(
    const __hip_bfloat16* __restrict__ in_cl,
    const __hip_bfloat16* __restrict__ wTs,   // swizzled (27*4096)
    const float* __restrict__ bias,
    __hip_bfloat16* __restrict__ out_cl_b16) {
    __shared__ __hip_bfloat16 ts[32 * 72];    // 4608B bounce

    const int tid = threadIdx.x;
    const int wv = tid >> 6;
    const int lane = tid & 63;
    const int l15 = lane & 15;
    const int quad = lane >> 4;
    const int wh = blockIdx.x & 1;
    const int h = (blockIdx.x >> 1) & 63;
    const int t = blockIdx.x >> 7;
    const int w0 = wh * 32;
    const int pg = wv >> 1;
    const int chf = wv & 1;
    const int wpos = w0 + pg * 16 + l15;
    const int posbase = t * HW_ + h * W_;

    floatx4 acc0 = (floatx4){0.f, 0.f, 0.f, 0.f};
    floatx4 acc1 = (floatx4){0.f, 0.f, 0.f, 0.f};
    const bf16x8 z = {};
    const __hip_bfloat16* wb = wTs + chf * 2048 + lane * 8;

    const int ktlo = (t == 0) ? 1 : 0;
    const int kthi = (t == T_ - 1) ? 2 : 3;

    for (int kt = ktlo; kt < kthi; ++kt) {
        const int t_in = t - 1 + kt;
#pragma unroll 1
        for (int kh = 0; kh < 3; ++kh) {
            const int h_in = h - 1 + kh;
            if ((unsigned)h_in >= H_) continue;
            const int rowbase = t_in * HW_ + h_in * W_;
#pragma unroll
            for (int kw = 0; kw < 3; ++kw) {
                const int tap = kt * 9 + kh * 3 + kw;
                const int w_in = wpos - 1 + kw;
                const bool v = (unsigned)w_in < W_;
                const int wc = v ? w_in : 0;
                const __hip_bfloat16* ap = in_cl + (rowbase + wc) * C_ + quad * 8;
                bf16x8 a0 = *(const bf16x8*)(ap);
                bf16x8 a1 = *(const bf16x8*)(ap + 32);
                a0 = v ? a0 : z;
                a1 = v ? a1 : z;
                const __hip_bfloat16* bp = wb + tap * 4096;
                const bf16x8 b00 = *(const bf16x8*)(bp);
                const bf16x8 b01 = *(const bf16x8*)(bp + 512);
                const bf16x8 b10 = *(const bf16x8*)(bp + 1024);
                const bf16x8 b11 = *(const bf16x8*)(bp + 1536);
                acc0 = __builtin_amdgcn_mfma_f32_16x16x32_bf16(a0, b00, acc0, 0, 0, 0);
                acc0 = __builtin_amdgcn_mfma_f32_16x16x32_bf16(a1, b01, acc0, 0, 0, 0);
                acc1 = __builtin_amdgcn_mfma_f32_16x16x32_bf16(a0, b10, acc1, 0, 0, 0);
                acc1 = __builtin_amdgcn_mfma_f32_16x16x32_bf16(a1, b11, acc1, 0, 0, 0);
            }
        }
    }

    const int n0 = chf * 32 + l15;
    const float bv0 = bias[n0], bv1 = bias[n0 + 16];
#pragma unroll
    for (int r = 0; r < 4; ++r) {
        const int p = pg * 16 + quad * 4 + r;
        float v0 = acc0[r] + bv0;
        v0 = (v0 >= 0.f) ? v0 : 0.01f * v0;
        float v1 = acc1[r] + bv1;
        v1 = (v1 >= 0.f) ? v1 : 0.01f * v1;
        ts[p * 72 + n0] = __float2bfloat16(v0);
        ts[p * 72 + n0 + 16] = __float2bfloat16(v1);
    }
    __syncthreads();
    {
        const int p = tid >> 3, ck = tid & 7;
        const uint4 v4 = *(const uint4*)&ts[p * 72 + ck * 8];
        *(uint4*)&out_cl_b16[(posbase + w0 + p) * C_ + ck * 8] = v4;
    }
}

// ---------------------------------------------------------------------------
// FUSED offsets-conv + deformable conv + 1x1 residual (R17).
//  Phase 1: per-wave streaming MFMA offsets conv -> LDS offs[32][56] (R12).
//  Phase 2: R12 deform with the step REORDERED so gathers are issued
//   POST-barrier: barrier -> MFMA(k) -> gather(k+2) -> blend(k+1) ->
//   store(k+1). R12 issued gather(k+2) immediately pre-barrier, so the
//   compiler's mandatory `s_waitcnt vmcnt(0)` before `s_barrier` drained
//   them at FULL latency every tap (why 2-deep never beat 1-deep: 67us
//   plateau). Post-barrier issue gives gathers ~blend+store+MFMA of cover
//   before the next tap's drain. Dbuf safety: store into buf[k+1] after
//   barrier_k is safe (barrier_k closed all MFMA(k-1) reads of that
//   buffer); barrier_{k+1} publishes it.
// ---------------------------------------------------------------------------
struct Gath {
    bf16x8 c00, c01, c10, c11;
    float w00, w01, w10, w11;
};

__global__ __launch_bounds__(256) void deform_fused_kernel(
    const __hip_bfloat16* __restrict__ y1b,
    const __hip_bfloat16* __restrict__ woffs, const float* __restrict__ boff,
    const __hip_bfloat16* __restrict__ wds, const float* __restrict__ bd,
    const __hip_bfloat16* __restrict__ xclb, const __hip_bfloat16* __restrict__ wrs,
    const float* __restrict__ br, float* __restrict__ out) {
    __shared__ __hip_bfloat16 Abuf[2][32 * CHS];     // 8960 B
    __shared__ float offs[32 * OSTR];                // 7168 B

    const int tid = threadIdx.x;
    const int wv = tid >> 6;
    const int lane = tid & 63;
    const int l15 = lane & 15;
    const int quad = lane >> 4;
    const int wh = blockIdx.x & 1;
    const int h = (blockIdx.x >> 1) & 63;
    const int t = blockIdx.x >> 7;
    const int w0 = wh * 32;
    const int n = wv * 16 + l15;
    const int posbase = t * HW_ + h * W_ + w0;
    const int cpos = tid >> 3;               // position 0..31
    const int c8 = tid & 7;                  // 8-ch chunk

    // ================= Phase 1: offsets conv -> LDS (R12) =================
    {
        const int pg = wv >> 1;
        const int chf = wv & 1;
        const int wpos = w0 + pg * 16 + l15;
        floatx4 oa0 = (floatx4){0.f, 0.f, 0.f, 0.f};
        floatx4 oa1 = (floatx4){0.f, 0.f, 0.f, 0.f};
        const bf16x8 z = {};
        const __hip_bfloat16* wb = woffs + chf * 2048 + lane * 8;
        const int ktlo = (t == 0) ? 1 : 0;
        const int kthi = (t == T_ - 1) ? 2 : 3;

        for (int kt = ktlo; kt < kthi; ++kt) {
            const int t_in = t - 1 + kt;
#pragma unroll 1
            for (int kh = 0; kh < 3; ++kh) {
                const int h_in = h - 1 + kh;
                if ((unsigned)h_in >= H_) continue;
                const int rowbase = t_in * HW_ + h_in * W_;
#pragma unroll
                for (int kw = 0; kw < 3; ++kw) {
                    const int tap = kt * 9 + kh * 3 + kw;
                    const int w_in = wpos - 1 + kw;
                    const bool v = (unsigned)w_in < W_;
                    const int wc = v ? w_in : 0;
                    const __hip_bfloat16* ap = y1b + (rowbase + wc) * C_ + quad * 8;
                    bf16x8 a0 = *(const bf16x8*)(ap);
                    bf16x8 a1 = *(const bf16x8*)(ap + 32);
                    a0 = v ? a0 : z;
                    a1 = v ? a1 : z;
                    const __hip_bfloat16* bp = wb + tap * 4096;
                    const bf16x8 b00 = *(const bf16x8*)(bp);
                    const bf16x8 b01 = *(const bf16x8*)(bp + 512);
                    const bf16x8 b10 = *(const bf16x8*)(bp + 1024);
                    const bf16x8 b11 = *(const bf16x8*)(bp + 1536);
                    oa0 = __builtin_amdgcn_mfma_f32_16x16x32_bf16(a0, b00, oa0, 0, 0, 0);
                    oa0 = __builtin_amdgcn_mfma_f32_16x16x32_bf16(a1, b01, oa0, 0, 0, 0);
                    oa1 = __builtin_amdgcn_mfma_f32_16x16x32_bf16(a0, b10, oa1, 0, 0, 0);
                    oa1 = __builtin_amdgcn_mfma_f32_16x16x32_bf16(a1, b11, oa1, 0, 0, 0);
                }
            }
        }
        const int n0 = chf * 32 + l15;                // 0..15 or 32..47 (<54)
        const float bv0 = boff[n0];
        const float bv1 = (n0 + 16 < NOFF) ? boff[n0 + 16] : 0.f;
#pragma unroll
        for (int r = 0; r < 4; ++r) {
            const int p = pg * 16 + quad * 4 + r;
            offs[p * OSTR + n0] = oa0[r] + bv0;
            if (n0 + 16 < NOFF) offs[p * OSTR + n0 + 16] = oa1[r] + bv1;
        }
    }
    __syncthreads();

    // ================= Phase 2: deform, gathers issued POST-barrier ========
    floatx4 acc[2], racc[2];
#pragma unroll
    for (int m = 0; m < 2; ++m) {
        acc[m] = (floatx4){0.f, 0.f, 0.f, 0.f};
        racc[m] = (floatx4){0.f, 0.f, 0.f, 0.f};
    }

    // residual 1x1 conv on x (swizzled B, coalesced)
    {
        const bf16x8 rb0 = *(const bf16x8*)(wrs + wv * 1024 + lane * 8);
        const bf16x8 rb1 = *(const bf16x8*)(wrs + wv * 1024 + lane * 8 + 512);
#pragma unroll
        for (int m = 0; m < 2; ++m) {
            const __hip_bfloat16* ap = xclb + (posbase + m * 16 + l15) * C_ + quad * 8;
            const bf16x8 a0 = *(const bf16x8*)(ap);
            const bf16x8 a1 = *(const bf16x8*)(ap + 32);
            racc[m] = __builtin_amdgcn_mfma_f32_16x16x32_bf16(a0, rb0, racc[m], 0, 0, 0);
            racc[m] = __builtin_amdgcn_mfma_f32_16x16x32_bf16(a1, rb1, racc[m], 0, 0, 0);
        }
    }

    const int k0 = (t == 0) ? 9 : 0;
    const int k1 = (t == T_ - 1) ? 18 : KTAPS;

    auto load_off = [&](int k, float& dh, float& dw) {
        dh = offs[cpos * OSTR + 2 * k];
        dw = offs[cpos * OSTR + 2 * k + 1];
    };
    auto gather = [&](int k, float dh, float dw, Gath& g) {
        const int kt = k / 9, kh = (k / 3) % 3, kw = k % 3;
        const int t_in = t - 1 + kt;
        const float hs = (float)(h - 1 + kh) + dh;
        const float wsv = (float)(w0 + cpos - 1 + kw) + dw;
        const float h0f = floorf(hs), w0f = floorf(wsv);
        const float fh = hs - h0f, fw = wsv - w0f;
        const int h0i = (int)h0f, w0i = (int)w0f;
        const int h1i = h0i + 1, w1i = w0i + 1;
        const float m_h0 = ((unsigned)h0i < H_) ? 1.f : 0.f;
        const float m_h1 = ((unsigned)h1i < H_) ? 1.f : 0.f;
        const float m_w0 = ((unsigned)w0i < W_) ? 1.f : 0.f;
        const float m_w1 = ((unsigned)w1i < W_) ? 1.f : 0.f;
        g.w00 = (1.f - fh) * (1.f - fw) * m_h0 * m_w0;
        g.w01 = (1.f - fh) * fw * m_h0 * m_w1;
        g.w10 = fh * (1.f - fw) * m_h1 * m_w0;
        g.w11 = fh * fw * m_h1 * m_w1;
        const int h0c = min(max(h0i, 0), H_ - 1);
        const int h1c = min(max(h1i, 0), H_ - 1);
        const int w0c = min(max(w0i, 0), W_ - 1);
        const int w1c = min(max(w1i, 0), W_ - 1);
        const int tb = t_in * HW_;
        g.c00 = *(const bf16x8*)(y1b + (tb + h0c * W_ + w0c) * C_ + c8 * 8);
        g.c01 = *(const bf16x8*)(y1b + (tb + h0c * W_ + w1c) * C_ + c8 * 8);
        g.c10 = *(const bf16x8*)(y1b + (tb + h1c * W_ + w0c) * C_ + c8 * 8);
        g.c11 = *(const bf16x8*)(y1b + (tb + h1c * W_ + w1c) * C_ + c8 * 8);
    };
    auto blend = [&](const Gath& g, bf16x8& o) {
        union U { bf16x8 v; __hip_bfloat16 e[8]; };
        U a00, a01, a10, a11, r;
        a00.v = g.c00; a01.v = g.c01; a10.v = g.c10; a11.v = g.c11;
#pragma unroll
        for (int j = 0; j < 8; ++j) {
            float f = g.w00 * __bfloat162float(a00.e[j]) + g.w01 * __bfloat162float(a01.e[j]) +
                      g.w10 * __bfloat162float(a10.e[j]) + g.w11 * __bfloat162float(a11.e[j]);
            r.e[j] = __float2bfloat16(f);
        }
        o = r.v;
    };
    auto loadBd = [&](int k, bf16x8& B0, bf16x8& B1) {
        const __hip_bfloat16* p = wds + k * 4096 + wv * 1024 + lane * 8;
        B0 = *(const bf16x8*)(p);
        B1 = *(const bf16x8*)(p + 512);
    };

    // named pipeline state (no dynamically-indexed arrays -> no spill)
    Gath gA, gB;
    bf16x8 bl;
    bf16x8 cb0, cb1, nb0, nb1;
    float oh2, ow2;

    // Reordered step: barrier FIRST, then MFMA(k), then issue gather(k+2),
    // then blend(k+1) + store into the other buffer.
    auto step = [&](int k, __hip_bfloat16* bufk, __hip_bfloat16* bufn,
                    Gath& gSelf, Gath& gOther) {
        __syncthreads();                          // publishes store(k); drains loads issued LAST tap (covered)

        const bf16x8 b0 = cb0;
        const bf16x8 b1 = cb1;
#pragma unroll
        for (int m = 0; m < 2; ++m) {
            const __hip_bfloat16* ap = bufk + (m * 16 + l15) * CHS + quad * 8;
            const bf16x8 a0 = *(const bf16x8*)(ap);
            const bf16x8 a1 = *(const bf16x8*)(ap + 32);
            acc[m] = __builtin_amdgcn_mfma_f32_16x16x32_bf16(a0, b0, acc[m], 0, 0, 0);
            acc[m] = __builtin_amdgcn_mfma_f32_16x16x32_bf16(a1, b1, acc[m], 0, 0, 0);
        }
        if (k + 2 < k1) {
            gather(k + 2, oh2, ow2, gSelf);       // POST-barrier issue: ~blend+store+MFMA of cover
            if (k + 3 < k1) load_off(k + 3, oh2, ow2);
        }
        if (k + 1 < k1) {
            blend(gOther, bl);                    // consumes gather(k+1), issued last tap
            *(bf16x8*)&bufn[cpos * CHS + c8 * 8] = bl;   // store tap k+1 panel (safe post-barrier_k)
            cb0 = nb0; cb1 = nb1;
            if (k + 2 < k1) loadBd(k + 2, nb0, nb1);
        }
    };

    // prologue: gathers 2 taps deep, B 1 tap deep; store tap-k0 panel pre-loop
    {
        float dh0, dw0, dh1, dw1;
        load_off(k0, dh0, dw0);
        load_off(k0 + 1, dh1, dw1);
        load_off(k0 + 2, oh2, ow2);
        gather(k0, dh0, dw0, gA);
        gather(k0 + 1, dh1, dw1, gB);
        loadBd(k0, cb0, cb1);
        loadBd(k0 + 1, nb0, nb1);
        blend(gA, bl);
        *(bf16x8*)&Abuf[0][cpos * CHS + c8 * 8] = bl;
    }

    // main loop, 2x unrolled: even kr -> (buf0, gA), odd kr -> (buf1, gB)
    int k = k0;
    for (; k + 1 < k1; k += 2) {
        step(k, Abuf[0], Abuf[1], gA, gB);
        step(k + 1, Abuf[1], Abuf[0], gB, gA);
    }
    if (k < k1) step(k, Abuf[0], Abuf[1], gA, gB);   // tail (27-tap: kr even -> gA/buf0)

    // epilogue: lrelu(deform + bd) + (residual + br)
    const float bdv = bd[n];
    const float brv = br[n];
#pragma unroll
    for (int m = 0; m < 2; ++m) {
        floatx4 o;
#pragma unroll
        for (int r = 0; r < 4; ++r) {
            float v = acc[m][r] + bdv;
            v = (v >= 0.f) ? v : 0.01f * v;
            o[r] = v + racc[m][r] + brv;
        }
        *(floatx4*)&out[n * THW_ + posbase + m * 16 + quad * 4] = o;
    }
}

// ---------------------------------------------------------------------------
extern "C" void kernel_launch(void* const* d_in, const int* in_sizes, int n_in,
                              void* d_out, int out_size, void* d_ws, size_t ws_size,
                              hipStream_t stream) {
    const float* x    = (const float*)d_in[0];
    const float* W1   = (const float*)d_in[1];
    const float* b1   = (const float*)d_in[2];
    const float* Woff = (const float*)d_in[3];
    const float* boff = (const float*)d_in[4];
    const float* Wd   = (const float*)d_in[5];
    const float* bd   = (const float*)d_in[6];
    const float* Wr   = (const float*)d_in[7];
    const float* br   = (const float*)d_in[8];
    float* out = (float*)d_out;

    float* ws = (float*)d_ws;
    __hip_bfloat16* xclb  = (__hip_bfloat16*)(ws);             // 2,097,152 bf16
    __hip_bfloat16* y1b   = (__hip_bfloat16*)(ws + 1048576);   // 2,097,152 bf16
    __hip_bfloat16* w1s   = (__hip_bfloat16*)(ws + 2097152);   //   110,592 bf16
    __hip_bfloat16* woffs = (__hip_bfloat16*)(ws + 2152448);   //   110,592 bf16
    __hip_bfloat16* wdsb  = (__hip_bfloat16*)(ws + 2207744);   //   110,592 bf16
    __hip_bfloat16* wrsb  = (__hip_bfloat16*)(ws + 2263040);   //     4,096 bf16
    // total ~9.1 MB

    prep_tocl_kernel<<<THW_ / 64, 256, 0, stream>>>(
        x, xclb, W1, Woff, Wd, Wr, w1s, woffs, wdsb, wrsb);

    conv_stream_kernel<<<dim3(T_ * H_ * 2), 256, 0, stream>>>(
        xclb, w1s, b1, y1b);

    deform_fused_kernel<<<dim3(T_ * H_ * 2), 256, 0, stream>>>(
        y1b, woffs, boff, wdsb, bd, xclb, wrsb, br, out);
}